// Round 1
// baseline (411.914 us; speedup 1.0000x reference)
//
#include <hip/hip_runtime.h>

// IRevNetSqueeze forward = pixel-unshuffle (block 2):
//   out[b, 4c + 2i + j, ho, wo] = x[b, c, 2*ho + i, 2*wo + j]
// B=16, C=16, H=512, W=512 -> out (16, 64, 256, 256), fp32.
//
// Strategy: each thread loads one float4 of an input row (4 consecutive w).
//   elements {x.x, x.z} (even w)  -> channel j=0, wo = {2w4, 2w4+1}  (contiguous float2)
//   elements {x.y, x.w} (odd  w)  -> channel j=1, same wo pair        (contiguous float2)
// => 16B coalesced read + 2x 8B coalesced writes per lane; every fetched
//    byte used exactly once. Pure HBM-bound permutation.

__global__ __launch_bounds__(256) void IRevNetSqueeze_52441550684474_kernel(
    const float4* __restrict__ x, float2* __restrict__ out) {
    const int tid = blockIdx.x * blockDim.x + threadIdx.x;  // [0, 16777216)

    const float4 v = x[tid];

    const int w4   = tid & 127;    // float4 index within input row (W/4 = 128)
    const int row  = tid >> 7;     // (b*16 + c)*512 + h_in
    const int h_in = row & 511;
    const int bc   = row >> 9;     // b*16 + c
    const int ho   = h_in >> 1;
    const int i    = h_in & 1;

    // global output channel for j=0: b*64 + 4c + 2i = 4*bc + 2i
    const int oc = 4 * bc + 2 * i;

    // float2 index: (((oc+j)*256 + ho)*256 + 2*w4) / 2
    const int o = (oc * 256 + ho) * 128 + w4;

    out[o]         = make_float2(v.x, v.z);  // j = 0
    out[o + 32768] = make_float2(v.y, v.w);  // j = 1  (+256*128 float2 = one channel plane)
}

extern "C" void kernel_launch(void* const* d_in, const int* in_sizes, int n_in,
                              void* d_out, int out_size, void* d_ws, size_t ws_size,
                              hipStream_t stream) {
    const float4* x = (const float4*)d_in[0];
    float2* out = (float2*)d_out;

    // total float4 elements = 16*16*512*512 / 4 = 16,777,216 ; exact multiple of 256
    const int n4 = in_sizes[0] / 4;
    const int block = 256;
    const int grid = n4 / block;  // 65536

    IRevNetSqueeze_52441550684474_kernel<<<grid, block, 0, stream>>>(x, out);
}